// Round 1
// 2705.315 us; speedup vs baseline: 1.6558x; 1.6558x over previous
//
#include <hip/hip_runtime.h>
#include <math.h>

#define B_  16
#define S_  2048
#define D_  768
#define H_  12
#define DK_ 64
#define L_  307
constexpr float INV_SCALE = 0.125f;  // 1/sqrt(64)

typedef float nfloat4 __attribute__((ext_vector_type(4)));

// ---------------------------------------------------------------------------
// Top-k: one block per batch. Bitonic sort 2048 (val,idx) pairs in LDS,
// descending by value, ties broken by ascending index (jax.lax.top_k order).
// cls_attention = rollout[b, 0, 1:]  (2047 elems, padded to 2048 with -inf).
// ---------------------------------------------------------------------------
__global__ __launch_bounds__(256) void topk_kernel(const float* __restrict__ rollout,
                                                   int* __restrict__ top_idx) {
  __shared__ float sval[2048];
  __shared__ int   sidx[2048];
  const int b = blockIdx.x;
  const int t = threadIdx.x;
  const float* row = rollout + (size_t)b * S_ * S_;  // row 0 of batch b
  for (int i = t; i < 2048; i += 256) {
    if (i < S_ - 1) { sval[i] = row[i + 1]; sidx[i] = i + 1; }
    else            { sval[i] = -INFINITY;  sidx[i] = 0x7FFFFFFF; }
  }
  __syncthreads();
  for (int k = 2; k <= 2048; k <<= 1) {
    for (int j = k >> 1; j > 0; j >>= 1) {
      for (int i = t; i < 2048; i += 256) {
        const int ixj = i ^ j;
        if (ixj > i) {
          const float v1 = sval[i], v2 = sval[ixj];
          const int   i1 = sidx[i], i2 = sidx[ixj];
          bool sw;
          if ((i & k) == 0) sw = (v2 > v1) || (v2 == v1 && i2 < i1);  // descending seg
          else              sw = (v1 > v2) || (v1 == v2 && i1 < i2);  // ascending seg
          if (sw) { sval[i] = v2; sval[ixj] = v1; sidx[i] = i2; sidx[ixj] = i1; }
        }
      }
      __syncthreads();
    }
  }
  for (int i = t; i < L_; i += 256) top_idx[b * L_ + i] = sidx[i];
}

// ---------------------------------------------------------------------------
// Gather x_local[b,l,:] = x[b, top_idx[b,l], :]
// ---------------------------------------------------------------------------
__global__ __launch_bounds__(192) void gather_kernel(const float* __restrict__ x,
                                                     const int* __restrict__ top_idx,
                                                     float* __restrict__ x_local) {
  const int row = blockIdx.x;          // b*L_ + l
  const int b   = row / L_;
  const int src = top_idx[row];
  const float4* xs = (const float4*)(x + ((size_t)b * S_ + src) * D_);
  float4*       xd = (float4*)(x_local + (size_t)row * D_);
  xd[threadIdx.x] = xs[threadIdx.x];   // 192 * float4 = 768 floats
}

// ---------------------------------------------------------------------------
// fp32 GEMM: C[m,e] = sum_d A[m,d] * W[e,d]   (A: M x 768, W: 768 x 768)
// 64x64 block tile, BK=16, 256 threads, 4x4 micro-tile per thread.
// LDS layout [k][m]: float4 compute reads are 2-way-conflict max (free).
// ---------------------------------------------------------------------------
__global__ __launch_bounds__(256) void gemm_nt_kernel(const float* __restrict__ A,
                                                      const float* __restrict__ W,
                                                      float* __restrict__ C, int M) {
  __shared__ float As[16][64];
  __shared__ float Ws[16][64];
  const int t   = threadIdx.x;
  const int m0  = blockIdx.x * 64;
  const int n0  = blockIdx.y * 64;
  const int lm  = t >> 2;            // 0..63 (tile row being loaded)
  const int lk4 = (t & 3) << 2;      // 0,4,8,12 (k offset of the float4)
  const int tx  = t & 15, ty = t >> 4;
  float acc[4][4] = {};
  const int am = m0 + lm;
  const float* Arow = A + (size_t)am * D_ + lk4;
  const float* Wrow = W + (size_t)(n0 + lm) * D_ + lk4;
  for (int d0 = 0; d0 < D_; d0 += 16) {
    float4 av = make_float4(0.f, 0.f, 0.f, 0.f);
    if (am < M) av = *(const float4*)(Arow + d0);
    const float4 wv = *(const float4*)(Wrow + d0);
    __syncthreads();
    As[lk4 + 0][lm] = av.x; As[lk4 + 1][lm] = av.y; As[lk4 + 2][lm] = av.z; As[lk4 + 3][lm] = av.w;
    Ws[lk4 + 0][lm] = wv.x; Ws[lk4 + 1][lm] = wv.y; Ws[lk4 + 2][lm] = wv.z; Ws[lk4 + 3][lm] = wv.w;
    __syncthreads();
#pragma unroll
    for (int kk = 0; kk < 16; kk++) {
      const float4 a = *(const float4*)&As[kk][ty * 4];
      const float4 w = *(const float4*)&Ws[kk][tx * 4];
      const float* ap = (const float*)&a;
      const float* wp = (const float*)&w;
#pragma unroll
      for (int i = 0; i < 4; i++)
#pragma unroll
        for (int j = 0; j < 4; j++) acc[i][j] += ap[i] * wp[j];
    }
  }
#pragma unroll
  for (int i = 0; i < 4; i++) {
    const int m = m0 + ty * 4 + i;
    if (m < M)
      *(float4*)(C + (size_t)m * D_ + n0 + tx * 4) =
          make_float4(acc[i][0], acc[i][1], acc[i][2], acc[i][3]);
  }
}

// ---------------------------------------------------------------------------
// Fused flash attention, two passes over S.
//  Pass A: online (rowmax, sum-exp) stats entirely in registers.
//  Pass B: recompute QK^T (K hot in L2), write normalized local_attention
//          ONCE (nontemporal), accumulate ctx += P*V via LDS round-trip.
// Grid: 960 linear blocks, id = lt*192 + (b*12+h) so the 5 l-tiles of one
// (b,h) share an XCD (id % 8 == bh % 8) and reuse the K/V slice in L2.
// LDS: Qs 16K + shared K/V buffer 16K + Ps 17K = 49 KB -> 3 blocks/CU.
// ---------------------------------------------------------------------------
__global__ __launch_bounds__(256, 3) void attn_kernel(const float* __restrict__ q,
                                                      const float* __restrict__ kmat,
                                                      const float* __restrict__ vmat,
                                                      float* __restrict__ att,
                                                      float* __restrict__ ctx) {
  __shared__ float Qs[64][64];    // [dk][l]
  __shared__ float KVs[64][64];   // K phase: [dk][s] ; V phase: [s][dk]
  __shared__ float Ps[64][68];    // [l][s], padded (16B-aligned rows)
  const int t   = threadIdx.x;
  const int bid = blockIdx.x;
  const int lt  = bid / 192;            // 0..4
  const int bh  = bid - lt * 192;       // 0..191
  const int h   = bh % H_;
  const int b   = bh / H_;
  const int l0  = lt * 64;
  const int tx  = t & 15, ty = t >> 4;
  const int lq  = t >> 2, cq = t & 3;

  // ---- load Q tile once: Qs[dk][l] ----
  {
    const int gl = l0 + lq;
#pragma unroll
    for (int p = 0; p < 4; p++) {
      const int dkc = (cq + 4 * p) * 4;
      float4 vq = make_float4(0.f, 0.f, 0.f, 0.f);
      if (gl < L_) vq = *(const float4*)(q + ((size_t)(b * L_ + gl)) * D_ + h * DK_ + dkc);
      Qs[dkc + 0][lq] = vq.x; Qs[dkc + 1][lq] = vq.y;
      Qs[dkc + 2][lq] = vq.z; Qs[dkc + 3][lq] = vq.w;
    }
  }

  auto loadK = [&](int s0) {
#pragma unroll
    for (int p = 0; p < 4; p++) {
      const int dkc = (cq + 4 * p) * 4;
      const float4 vk =
          *(const float4*)(kmat + ((size_t)(b * S_ + s0 + lq)) * D_ + h * DK_ + dkc);
      KVs[dkc + 0][lq] = vk.x; KVs[dkc + 1][lq] = vk.y;
      KVs[dkc + 2][lq] = vk.z; KVs[dkc + 3][lq] = vk.w;
    }
  };

  float m_run[4], s_run[4];
#pragma unroll
  for (int i = 0; i < 4; i++) { m_run[i] = -INFINITY; s_run[i] = 0.f; }

  // ================= Pass A: stats only =================
  for (int s0 = 0; s0 < S_; s0 += 64) {
    __syncthreads();
    loadK(s0);
    __syncthreads();
    float acc[4][4] = {};
#pragma unroll 8
    for (int dk = 0; dk < 64; dk++) {
      const float4 a = *(const float4*)&Qs[dk][ty * 4];
      const float4 w = *(const float4*)&KVs[dk][tx * 4];
      const float* ap = (const float*)&a;
      const float* wp = (const float*)&w;
#pragma unroll
      for (int i = 0; i < 4; i++)
#pragma unroll
        for (int j = 0; j < 4; j++) acc[i][j] += ap[i] * wp[j];
    }
#pragma unroll
    for (int i = 0; i < 4; i++) {
      const float v0 = acc[i][0] * INV_SCALE, v1 = acc[i][1] * INV_SCALE;
      const float v2 = acc[i][2] * INV_SCALE, v3 = acc[i][3] * INV_SCALE;
      const float mt = fmaxf(fmaxf(v0, v1), fmaxf(v2, v3));
      if (mt > m_run[i]) { s_run[i] *= __expf(m_run[i] - mt); m_run[i] = mt; }
      s_run[i] += __expf(v0 - m_run[i]) + __expf(v1 - m_run[i]) +
                  __expf(v2 - m_run[i]) + __expf(v3 - m_run[i]);
    }
  }
  // cross-lane (tx group, 16 lanes) reduction of the per-strip stats
#pragma unroll
  for (int i = 0; i < 4; i++) {
    float m = m_run[i];
#pragma unroll
    for (int o = 1; o < 16; o <<= 1) m = fmaxf(m, __shfl_xor(m, o));
    float s = s_run[i] * __expf(m_run[i] - m);
#pragma unroll
    for (int o = 1; o < 16; o <<= 1) s += __shfl_xor(s, o);
    m_run[i] = m;
    s_run[i] = 1.f / s;   // now holds inv_sum
  }

  // ================= Pass B: normalize + write att + P*V =================
  float ctxacc[4][4] = {};
  const size_t att_row0 = (size_t)(b * H_ + h) * L_;
  for (int s0 = 0; s0 < S_; s0 += 64) {
    __syncthreads();                       // prev PV done with KVs(V), Ps
    loadK(s0);
    __syncthreads();
    float acc[4][4] = {};
#pragma unroll 8
    for (int dk = 0; dk < 64; dk++) {
      const float4 a = *(const float4*)&Qs[dk][ty * 4];
      const float4 w = *(const float4*)&KVs[dk][tx * 4];
      const float* ap = (const float*)&a;
      const float* wp = (const float*)&w;
#pragma unroll
      for (int i = 0; i < 4; i++)
#pragma unroll
        for (int j = 0; j < 4; j++) acc[i][j] += ap[i] * wp[j];
    }
#pragma unroll
    for (int i = 0; i < 4; i++) {
      float4 pv;
      pv.x = __expf(acc[i][0] * INV_SCALE - m_run[i]) * s_run[i];
      pv.y = __expf(acc[i][1] * INV_SCALE - m_run[i]) * s_run[i];
      pv.z = __expf(acc[i][2] * INV_SCALE - m_run[i]) * s_run[i];
      pv.w = __expf(acc[i][3] * INV_SCALE - m_run[i]) * s_run[i];
      *(float4*)&Ps[ty * 4 + i][tx * 4] = pv;
      const int gl = l0 + ty * 4 + i;
      if (gl < L_) {
        nfloat4* ap = (nfloat4*)(att + (att_row0 + gl) * S_ + s0 + tx * 4);
        __builtin_nontemporal_store(*(const nfloat4*)&pv, ap);  // write-once stream
      }
    }
    __syncthreads();                       // Ps ready; KVs(K) no longer needed
    {
      const int c = t & 15, lr = t >> 4;   // V tile: KVs[s][dk]
#pragma unroll
      for (int p = 0; p < 4; p++) {
        const int s = lr + 16 * p;
        const float4 vv =
            *(const float4*)(vmat + ((size_t)(b * S_ + s0 + s)) * D_ + h * DK_ + c * 4);
        *(float4*)&KVs[s][c * 4] = vv;
      }
    }
    __syncthreads();
#pragma unroll 8
    for (int s = 0; s < 64; s++) {
      const float p0 = Ps[ty * 4 + 0][s];
      const float p1 = Ps[ty * 4 + 1][s];
      const float p2 = Ps[ty * 4 + 2][s];
      const float p3 = Ps[ty * 4 + 3][s];
      const float4 vv = *(const float4*)&KVs[s][tx * 4];
      const float* vp = (const float*)&vv;
#pragma unroll
      for (int j = 0; j < 4; j++) {
        ctxacc[0][j] += p0 * vp[j];
        ctxacc[1][j] += p1 * vp[j];
        ctxacc[2][j] += p2 * vp[j];
        ctxacc[3][j] += p3 * vp[j];
      }
    }
  }
#pragma unroll
  for (int i = 0; i < 4; i++) {
    const int gl = l0 + ty * 4 + i;
    if (gl < L_)
      *(float4*)(ctx + ((size_t)(b * L_ + gl)) * D_ + h * DK_ + tx * 4) =
          make_float4(ctxacc[i][0], ctxacc[i][1], ctxacc[i][2], ctxacc[i][3]);
  }
}

// ---------------------------------------------------------------------------
extern "C" void kernel_launch(void* const* d_in, const int* in_sizes, int n_in,
                              void* d_out, int out_size, void* d_ws, size_t ws_size,
                              hipStream_t stream) {
  const float* x    = (const float*)d_in[0];
  const float* roll = (const float*)d_in[1];
  const float* Wq   = (const float*)d_in[2];
  const float* Wk   = (const float*)d_in[3];
  const float* Wv   = (const float*)d_in[4];
  const float* Wo   = (const float*)d_in[5];
  float* out = (float*)d_out;
  float* att = out + (size_t)B_ * L_ * D_;   // local_attention region of d_out

  char* ws = (char*)d_ws;
  size_t off = 0;
  auto take = [&](size_t bytes) -> void* {
    void* p = ws + off;
    off = (off + bytes + 255) & ~(size_t)255;
    return p;
  };
  int*   top_idx = (int*)  take((size_t)B_ * L_ * sizeof(int));
  float* x_local = (float*)take((size_t)B_ * L_ * D_ * sizeof(float));
  float* qbuf    = (float*)take((size_t)B_ * L_ * D_ * sizeof(float));
  float* kbuf    = (float*)take((size_t)B_ * S_ * D_ * sizeof(float));
  float* vbuf    = (float*)take((size_t)B_ * S_ * D_ * sizeof(float));
  float* ctxbuf  = (float*)take((size_t)B_ * L_ * D_ * sizeof(float));
  (void)in_sizes; (void)n_in; (void)out_size; (void)ws_size;

  topk_kernel  <<<B_, 256, 0, stream>>>(roll, top_idx);
  gather_kernel<<<B_ * L_, 192, 0, stream>>>(x, top_idx, x_local);
  gemm_nt_kernel<<<dim3(512, 12), 256, 0, stream>>>(x, Wk, kbuf, B_ * S_);
  gemm_nt_kernel<<<dim3(512, 12), 256, 0, stream>>>(x, Wv, vbuf, B_ * S_);
  gemm_nt_kernel<<<dim3(77, 12),  256, 0, stream>>>(x_local, Wq, qbuf, B_ * L_);
  attn_kernel  <<<dim3(5 * 192), 256, 0, stream>>>(qbuf, kbuf, vbuf, att, ctxbuf);
  gemm_nt_kernel<<<dim3(77, 12),  256, 0, stream>>>(ctxbuf, Wo, out, B_ * L_);
}

// Round 3
// 2697.189 us; speedup vs baseline: 1.6608x; 1.0030x over previous
//
#include <hip/hip_runtime.h>
#include <math.h>

#define B_  16
#define S_  2048
#define D_  768
#define H_  12
#define DK_ 64
#define L_  307
constexpr float INV_SCALE = 0.125f;  // 1/sqrt(64), exact power of two

typedef float nfloat4 __attribute__((ext_vector_type(4)));

// ---------------------------------------------------------------------------
// Top-k: one block per batch. Bitonic sort 2048 (val,idx) pairs in LDS,
// descending by value, ties broken by ascending index (jax.lax.top_k order).
// ---------------------------------------------------------------------------
__global__ __launch_bounds__(256) void topk_kernel(const float* __restrict__ rollout,
                                                   int* __restrict__ top_idx) {
  __shared__ float sval[2048];
  __shared__ int   sidx[2048];
  const int b = blockIdx.x;
  const int t = threadIdx.x;
  const float* row = rollout + (size_t)b * S_ * S_;  // row 0 of batch b
  for (int i = t; i < 2048; i += 256) {
    if (i < S_ - 1) { sval[i] = row[i + 1]; sidx[i] = i + 1; }
    else            { sval[i] = -INFINITY;  sidx[i] = 0x7FFFFFFF; }
  }
  __syncthreads();
  for (int k = 2; k <= 2048; k <<= 1) {
    for (int j = k >> 1; j > 0; j >>= 1) {
      for (int i = t; i < 2048; i += 256) {
        const int ixj = i ^ j;
        if (ixj > i) {
          const float v1 = sval[i], v2 = sval[ixj];
          const int   i1 = sidx[i], i2 = sidx[ixj];
          bool sw;
          if ((i & k) == 0) sw = (v2 > v1) || (v2 == v1 && i2 < i1);  // descending seg
          else              sw = (v1 > v2) || (v1 == v2 && i1 < i2);  // ascending seg
          if (sw) { sval[i] = v2; sval[ixj] = v1; sidx[i] = i2; sidx[ixj] = i1; }
        }
      }
      __syncthreads();
    }
  }
  for (int i = t; i < L_; i += 256) top_idx[b * L_ + i] = sidx[i];
}

// ---------------------------------------------------------------------------
// Gather x_local[b,l,:] = x[b, top_idx[b,l], :]
// ---------------------------------------------------------------------------
__global__ __launch_bounds__(192) void gather_kernel(const float* __restrict__ x,
                                                     const int* __restrict__ top_idx,
                                                     float* __restrict__ x_local) {
  const int row = blockIdx.x;          // b*L_ + l
  const int b   = row / L_;
  const int src = top_idx[row];
  const float4* xs = (const float4*)(x + ((size_t)b * S_ + src) * D_);
  float4*       xd = (float4*)(x_local + (size_t)row * D_);
  xd[threadIdx.x] = xs[threadIdx.x];   // 192 * float4 = 768 floats
}

// ---------------------------------------------------------------------------
// fp32 GEMM 64x64 tile (kept for the small M=4912 GEMMs: more blocks).
// ---------------------------------------------------------------------------
__global__ __launch_bounds__(256) void gemm_nt_kernel(const float* __restrict__ A,
                                                      const float* __restrict__ W,
                                                      float* __restrict__ C, int M) {
  __shared__ float As[16][64];
  __shared__ float Ws[16][64];
  const int t   = threadIdx.x;
  const int m0  = blockIdx.x * 64;
  const int n0  = blockIdx.y * 64;
  const int lm  = t >> 2;
  const int lk4 = (t & 3) << 2;
  const int tx  = t & 15, ty = t >> 4;
  float acc[4][4] = {};
  const int am = m0 + lm;
  const float* Arow = A + (size_t)am * D_ + lk4;
  const float* Wrow = W + (size_t)(n0 + lm) * D_ + lk4;
  for (int d0 = 0; d0 < D_; d0 += 16) {
    float4 av = make_float4(0.f, 0.f, 0.f, 0.f);
    if (am < M) av = *(const float4*)(Arow + d0);
    const float4 wv = *(const float4*)(Wrow + d0);
    __syncthreads();
    As[lk4 + 0][lm] = av.x; As[lk4 + 1][lm] = av.y; As[lk4 + 2][lm] = av.z; As[lk4 + 3][lm] = av.w;
    Ws[lk4 + 0][lm] = wv.x; Ws[lk4 + 1][lm] = wv.y; Ws[lk4 + 2][lm] = wv.z; Ws[lk4 + 3][lm] = wv.w;
    __syncthreads();
#pragma unroll
    for (int kk = 0; kk < 16; kk++) {
      const float4 a = *(const float4*)&As[kk][ty * 4];
      const float4 w = *(const float4*)&Ws[kk][tx * 4];
      const float* ap = (const float*)&a;
      const float* wp = (const float*)&w;
#pragma unroll
      for (int i = 0; i < 4; i++)
#pragma unroll
        for (int j = 0; j < 4; j++) acc[i][j] += ap[i] * wp[j];
    }
  }
#pragma unroll
  for (int i = 0; i < 4; i++) {
    const int m = m0 + ty * 4 + i;
    if (m < M)
      *(float4*)(C + (size_t)m * D_ + n0 + tx * 4) =
          make_float4(acc[i][0], acc[i][1], acc[i][2], acc[i][3]);
  }
}

// ---------------------------------------------------------------------------
// fp32 GEMM 128x128 tile for the big M=32768 GEMMs. 256 threads, 8x8
// micro-tile split as 2x2 blocks of 4x4 (keeps LDS reads 2-way = free).
// Stride-132 LDS padding makes the transposed staging writes 2-way too.
// Register prefetch of the next k-slab hides global latency.
// ---------------------------------------------------------------------------
__global__ __launch_bounds__(256) void gemm128_nt_kernel(const float* __restrict__ A,
                                                         const float* __restrict__ W,
                                                         float* __restrict__ C, int M) {
  __shared__ float As[16][132];
  __shared__ float Ws[16][132];
  const int t   = threadIdx.x;
  const int m0  = blockIdx.x * 128;
  const int n0  = blockIdx.y * 128;
  const int tx  = t & 15, ty = t >> 4;
  const int lr  = t >> 2;            // 0..63
  const int lk4 = (t & 3) << 2;      // 0,4,8,12
  float acc[2][2][4][4] = {};
  const bool a0ok = (m0 + lr) < M, a1ok = (m0 + 64 + lr) < M;
  const float* Arow0 = A + (size_t)(m0 + lr) * D_ + lk4;
  const float* Arow1 = Arow0 + (size_t)64 * D_;
  const float* Wrow0 = W + (size_t)(n0 + lr) * D_ + lk4;
  const float* Wrow1 = Wrow0 + (size_t)64 * D_;
  float4 a0, a1, w0, w1;
  auto issue = [&](int d0) {
    a0 = a0ok ? *(const float4*)(Arow0 + d0) : make_float4(0.f, 0.f, 0.f, 0.f);
    a1 = a1ok ? *(const float4*)(Arow1 + d0) : make_float4(0.f, 0.f, 0.f, 0.f);
    w0 = *(const float4*)(Wrow0 + d0);
    w1 = *(const float4*)(Wrow1 + d0);
  };
  issue(0);
  for (int d0 = 0; d0 < D_; d0 += 16) {
    __syncthreads();
#pragma unroll
    for (int c = 0; c < 4; c++) {
      As[lk4 + c][lr]      = ((const float*)&a0)[c];
      As[lk4 + c][64 + lr] = ((const float*)&a1)[c];
      Ws[lk4 + c][lr]      = ((const float*)&w0)[c];
      Ws[lk4 + c][64 + lr] = ((const float*)&w1)[c];
    }
    __syncthreads();
    if (d0 + 16 < D_) issue(d0 + 16);   // prefetch next slab into regs
#pragma unroll
    for (int kk = 0; kk < 16; kk++) {
      const float4 av0 = *(const float4*)&As[kk][ty * 4];
      const float4 av1 = *(const float4*)&As[kk][64 + ty * 4];
      const float4 wv0 = *(const float4*)&Ws[kk][tx * 4];
      const float4 wv1 = *(const float4*)&Ws[kk][64 + tx * 4];
      const float* a0p = (const float*)&av0;
      const float* a1p = (const float*)&av1;
      const float* w0p = (const float*)&wv0;
      const float* w1p = (const float*)&wv1;
#pragma unroll
      for (int i = 0; i < 4; i++)
#pragma unroll
        for (int j = 0; j < 4; j++) {
          acc[0][0][i][j] += a0p[i] * w0p[j];
          acc[0][1][i][j] += a0p[i] * w1p[j];
          acc[1][0][i][j] += a1p[i] * w0p[j];
          acc[1][1][i][j] += a1p[i] * w1p[j];
        }
    }
  }
#pragma unroll
  for (int mi = 0; mi < 2; mi++)
#pragma unroll
    for (int i = 0; i < 4; i++) {
      const int m = m0 + mi * 64 + ty * 4 + i;
      if (m < M) {
        *(float4*)(C + (size_t)m * D_ + n0 + tx * 4) =
            make_float4(acc[mi][0][i][0], acc[mi][0][i][1], acc[mi][0][i][2], acc[mi][0][i][3]);
        *(float4*)(C + (size_t)m * D_ + n0 + 64 + tx * 4) =
            make_float4(acc[mi][1][i][0], acc[mi][1][i][1], acc[mi][1][i][2], acc[mi][1][i][3]);
      }
    }
}

// ---------------------------------------------------------------------------
// Fused flash attention, two passes over S.
//  - stride-68 LDS padding: staging writes + compute reads all <=2-way (free)
//  - Q pre-scaled by 1/8 (exact pow2, bit-identical results)
//  - register prefetch: next K (and V) tile issued before compute phases
//  - PV reads Ps as float4 (8 b128 per 64 FMA)
// LDS: 3 x 64x68 f32 = 52.2 KB -> 3 blocks/CU.
// ---------------------------------------------------------------------------
__global__ __launch_bounds__(256, 3) void attn_kernel(const float* __restrict__ q,
                                                      const float* __restrict__ kmat,
                                                      const float* __restrict__ vmat,
                                                      float* __restrict__ att,
                                                      float* __restrict__ ctx) {
  __shared__ float Qs[64][68];    // [dk][l]
  __shared__ float KVs[64][68];   // K phase: [dk][s] ; V phase: [s][dk]
  __shared__ float Ps[64][68];    // [l][s]
  const int t   = threadIdx.x;
  const int bid = blockIdx.x;
  const int lt  = bid / 192;            // 0..4
  const int bh  = bid - lt * 192;       // 0..191 -> same-XCD l-tiles per (b,h)
  const int h   = bh % H_;
  const int b   = bh / H_;
  const int l0  = lt * 64;
  const int tx  = t & 15, ty = t >> 4;
  const int lq  = t >> 2, cq = t & 3;

  // ---- load Q tile once, pre-scaled: Qs[dk][l] ----
  {
    const int gl = l0 + lq;
#pragma unroll
    for (int p = 0; p < 4; p++) {
      const int dkc = (cq + 4 * p) * 4;
      float4 vq = make_float4(0.f, 0.f, 0.f, 0.f);
      if (gl < L_) vq = *(const float4*)(q + ((size_t)(b * L_ + gl)) * D_ + h * DK_ + dkc);
      Qs[dkc + 0][lq] = vq.x * INV_SCALE; Qs[dkc + 1][lq] = vq.y * INV_SCALE;
      Qs[dkc + 2][lq] = vq.z * INV_SCALE; Qs[dkc + 3][lq] = vq.w * INV_SCALE;
    }
  }

  const float* kbase = kmat + ((size_t)b * S_ + lq) * D_ + h * DK_;
  float4 kreg[4];
  auto issueK = [&](int s0) {
#pragma unroll
    for (int p = 0; p < 4; p++)
      kreg[p] = *(const float4*)(kbase + (size_t)s0 * D_ + (cq + 4 * p) * 4);
  };
  auto writeK = [&]() {
#pragma unroll
    for (int p = 0; p < 4; p++) {
      const int dkc = (cq + 4 * p) * 4;
      KVs[dkc + 0][lq] = kreg[p].x; KVs[dkc + 1][lq] = kreg[p].y;
      KVs[dkc + 2][lq] = kreg[p].z; KVs[dkc + 3][lq] = kreg[p].w;
    }
  };
  auto qk = [&](float (&acc)[4][4]) {
#pragma unroll 8
    for (int dk = 0; dk < 64; dk++) {
      const float4 a = *(const float4*)&Qs[dk][ty * 4];
      const float4 w = *(const float4*)&KVs[dk][tx * 4];
      const float* ap = (const float*)&a;
      const float* wp = (const float*)&w;
#pragma unroll
      for (int i = 0; i < 4; i++)
#pragma unroll
        for (int j = 0; j < 4; j++) acc[i][j] += ap[i] * wp[j];
    }
  };

  float m_run[4], s_run[4];
#pragma unroll
  for (int i = 0; i < 4; i++) { m_run[i] = -INFINITY; s_run[i] = 0.f; }

  // ================= Pass A: stats only =================
  issueK(0);
  for (int s0 = 0; s0 < S_; s0 += 64) {
    __syncthreads();
    writeK();
    __syncthreads();
    issueK((s0 + 64) & (S_ - 1));   // prefetch next (wraps to 0 for pass B)
    float acc[4][4] = {};
    qk(acc);
#pragma unroll
    for (int i = 0; i < 4; i++) {
      const float v0 = acc[i][0], v1 = acc[i][1], v2 = acc[i][2], v3 = acc[i][3];
      const float mt = fmaxf(fmaxf(v0, v1), fmaxf(v2, v3));
      if (mt > m_run[i]) { s_run[i] *= __expf(m_run[i] - mt); m_run[i] = mt; }
      s_run[i] += __expf(v0 - m_run[i]) + __expf(v1 - m_run[i]) +
                  __expf(v2 - m_run[i]) + __expf(v3 - m_run[i]);
    }
  }
  // cross-lane (tx group, 16 lanes) reduction of the per-strip stats
#pragma unroll
  for (int i = 0; i < 4; i++) {
    float m = m_run[i];
#pragma unroll
    for (int o = 1; o < 16; o <<= 1) m = fmaxf(m, __shfl_xor(m, o));
    float s = s_run[i] * __expf(m_run[i] - m);
#pragma unroll
    for (int o = 1; o < 16; o <<= 1) s += __shfl_xor(s, o);
    m_run[i] = m;
    s_run[i] = 1.f / s;   // now holds inv_sum
  }

  // ================= Pass B: normalize + write att + P*V =================
  float ctxacc[4][4] = {};
  const size_t att_row0 = (size_t)(b * H_ + h) * L_;
  float4 vreg[4];
  auto issueV = [&](int s0) {
#pragma unroll
    for (int p = 0; p < 4; p++)
      vreg[p] = *(const float4*)(vmat + ((size_t)(b * S_ + s0 + ty + 16 * p)) * D_ +
                                 h * DK_ + tx * 4);
  };
  for (int s0 = 0; s0 < S_; s0 += 64) {
    __syncthreads();                       // prev PV done with KVs(V), Ps
    writeK();                              // kreg prefetched last iteration
    __syncthreads();
    issueV(s0);                            // V loads fly under QK compute
    float acc[4][4] = {};
    qk(acc);
#pragma unroll
    for (int i = 0; i < 4; i++) {
      float4 pv;
      pv.x = __expf(acc[i][0] - m_run[i]) * s_run[i];
      pv.y = __expf(acc[i][1] - m_run[i]) * s_run[i];
      pv.z = __expf(acc[i][2] - m_run[i]) * s_run[i];
      pv.w = __expf(acc[i][3] - m_run[i]) * s_run[i];
      *(float4*)&Ps[ty * 4 + i][tx * 4] = pv;
      const int gl = l0 + ty * 4 + i;
      if (gl < L_)
        __builtin_nontemporal_store(*(const nfloat4*)&pv,
            (nfloat4*)(att + (att_row0 + gl) * S_ + s0 + tx * 4));
    }
    __syncthreads();                       // Ps ready; KVs(K) no longer needed
#pragma unroll
    for (int p = 0; p < 4; p++)
      *(float4*)&KVs[ty + 16 * p][tx * 4] = vreg[p];
    __syncthreads();
    issueK((s0 + 64) & (S_ - 1));          // next K flies under PV compute
#pragma unroll 2
    for (int s4 = 0; s4 < 64; s4 += 4) {
      const float4 p0 = *(const float4*)&Ps[ty * 4 + 0][s4];
      const float4 p1 = *(const float4*)&Ps[ty * 4 + 1][s4];
      const float4 p2 = *(const float4*)&Ps[ty * 4 + 2][s4];
      const float4 p3 = *(const float4*)&Ps[ty * 4 + 3][s4];
      const float4 v0 = *(const float4*)&KVs[s4 + 0][tx * 4];
      const float4 v1 = *(const float4*)&KVs[s4 + 1][tx * 4];
      const float4 v2 = *(const float4*)&KVs[s4 + 2][tx * 4];
      const float4 v3 = *(const float4*)&KVs[s4 + 3][tx * 4];
#define PVROW(pi, r)                                                      \
      ctxacc[r][0] += pi.x * v0.x + pi.y * v1.x + pi.z * v2.x + pi.w * v3.x; \
      ctxacc[r][1] += pi.x * v0.y + pi.y * v1.y + pi.z * v2.y + pi.w * v3.y; \
      ctxacc[r][2] += pi.x * v0.z + pi.y * v1.z + pi.z * v2.z + pi.w * v3.z; \
      ctxacc[r][3] += pi.x * v0.w + pi.y * v1.w + pi.z * v2.w + pi.w * v3.w;
      PVROW(p0, 0) PVROW(p1, 1) PVROW(p2, 2) PVROW(p3, 3)
#undef PVROW
    }
  }
#pragma unroll
  for (int i = 0; i < 4; i++) {
    const int gl = l0 + ty * 4 + i;
    if (gl < L_)
      *(float4*)(ctx + ((size_t)(b * L_ + gl)) * D_ + h * DK_ + tx * 4) =
          make_float4(ctxacc[i][0], ctxacc[i][1], ctxacc[i][2], ctxacc[i][3]);
  }
}

// ---------------------------------------------------------------------------
extern "C" void kernel_launch(void* const* d_in, const int* in_sizes, int n_in,
                              void* d_out, int out_size, void* d_ws, size_t ws_size,
                              hipStream_t stream) {
  const float* x    = (const float*)d_in[0];
  const float* roll = (const float*)d_in[1];
  const float* Wq   = (const float*)d_in[2];
  const float* Wk   = (const float*)d_in[3];
  const float* Wv   = (const float*)d_in[4];
  const float* Wo   = (const float*)d_in[5];
  float* out = (float*)d_out;
  float* att = out + (size_t)B_ * L_ * D_;   // local_attention region of d_out

  char* ws = (char*)d_ws;
  size_t off = 0;
  auto take = [&](size_t bytes) -> void* {
    void* p = ws + off;
    off = (off + bytes + 255) & ~(size_t)255;
    return p;
  };
  int*   top_idx = (int*)  take((size_t)B_ * L_ * sizeof(int));
  float* x_local = (float*)take((size_t)B_ * L_ * D_ * sizeof(float));
  float* qbuf    = (float*)take((size_t)B_ * L_ * D_ * sizeof(float));
  float* kbuf    = (float*)take((size_t)B_ * S_ * D_ * sizeof(float));
  float* vbuf    = (float*)take((size_t)B_ * S_ * D_ * sizeof(float));
  float* ctxbuf  = (float*)take((size_t)B_ * L_ * D_ * sizeof(float));
  (void)in_sizes; (void)n_in; (void)out_size; (void)ws_size;

  topk_kernel  <<<B_, 256, 0, stream>>>(roll, top_idx);
  gather_kernel<<<B_ * L_, 192, 0, stream>>>(x, top_idx, x_local);
  gemm128_nt_kernel<<<dim3(256, 6), 256, 0, stream>>>(x, Wk, kbuf, B_ * S_);
  gemm128_nt_kernel<<<dim3(256, 6), 256, 0, stream>>>(x, Wv, vbuf, B_ * S_);
  gemm_nt_kernel<<<dim3(77, 12),  256, 0, stream>>>(x_local, Wq, qbuf, B_ * L_);
  attn_kernel  <<<dim3(5 * 192), 256, 0, stream>>>(qbuf, kbuf, vbuf, att, ctxbuf);
  gemm_nt_kernel<<<dim3(77, 12),  256, 0, stream>>>(ctxbuf, Wo, out, B_ * L_);
}

// Round 5
// 1996.005 us; speedup vs baseline: 2.2442x; 1.3513x over previous
//
#include <hip/hip_runtime.h>
#include <math.h>
#include <stdint.h>

#define B_  16
#define S_  2048
#define D_  768
#define H_  12
#define DK_ 64
#define L_  307
constexpr float INV_SCALE = 0.125f;  // 1/sqrt(64), exact power of two

typedef float nfloat4 __attribute__((ext_vector_type(4)));
typedef short short8v __attribute__((ext_vector_type(8)));   // 8 bf16 = 4 VGPRs
typedef float floatx4 __attribute__((ext_vector_type(4)));   // MFMA acc

// ---------------------------------------------------------------------------
// Top-k: one block per batch. Bitonic sort 2048 (val,idx) pairs in LDS,
// descending by value, ties broken by ascending index (jax.lax.top_k order).
// ---------------------------------------------------------------------------
__global__ __launch_bounds__(256) void topk_kernel(const float* __restrict__ rollout,
                                                   int* __restrict__ top_idx) {
  __shared__ float sval[2048];
  __shared__ int   sidx[2048];
  const int b = blockIdx.x;
  const int t = threadIdx.x;
  const float* row = rollout + (size_t)b * S_ * S_;  // row 0 of batch b
  for (int i = t; i < 2048; i += 256) {
    if (i < S_ - 1) { sval[i] = row[i + 1]; sidx[i] = i + 1; }
    else            { sval[i] = -INFINITY;  sidx[i] = 0x7FFFFFFF; }
  }
  __syncthreads();
  for (int k = 2; k <= 2048; k <<= 1) {
    for (int j = k >> 1; j > 0; j >>= 1) {
      for (int i = t; i < 2048; i += 256) {
        const int ixj = i ^ j;
        if (ixj > i) {
          const float v1 = sval[i], v2 = sval[ixj];
          const int   i1 = sidx[i], i2 = sidx[ixj];
          bool sw;
          if ((i & k) == 0) sw = (v2 > v1) || (v2 == v1 && i2 < i1);  // descending seg
          else              sw = (v1 > v2) || (v1 == v2 && i1 < i2);  // ascending seg
          if (sw) { sval[i] = v2; sval[ixj] = v1; sidx[i] = i2; sidx[ixj] = i1; }
        }
      }
      __syncthreads();
    }
  }
  for (int i = t; i < L_; i += 256) top_idx[b * L_ + i] = sidx[i];
}

// ---------------------------------------------------------------------------
// Gather x_local[b,l,:] = x[b, top_idx[b,l], :]
// ---------------------------------------------------------------------------
__global__ __launch_bounds__(192) void gather_kernel(const float* __restrict__ x,
                                                     const int* __restrict__ top_idx,
                                                     float* __restrict__ x_local) {
  const int row = blockIdx.x;          // b*L_ + l
  const int b   = row / L_;
  const int src = top_idx[row];
  const float4* xs = (const float4*)(x + ((size_t)b * S_ + src) * D_);
  float4*       xd = (float4*)(x_local + (size_t)row * D_);
  xd[threadIdx.x] = xs[threadIdx.x];   // 192 * float4 = 768 floats
}

// ---------------------------------------------------------------------------
// Split fp32 -> packed (bf16 hi | bf16 lo<<16), RNE both. hi+lo recovers the
// value to ~2^-17 relative; used by the split-bf16 MFMA GEMM (3-pass).
// ---------------------------------------------------------------------------
__device__ inline uint32_t split_pack(float v) {
  uint32_t b  = __float_as_uint(v);
  uint32_t hi = (b + 0x7FFFu + ((b >> 16) & 1u)) >> 16;      // RNE to bf16
  float    hf = __uint_as_float(hi << 16);
  float    r  = v - hf;                                      // exact (Sterbenz)
  uint32_t rb = __float_as_uint(r);
  uint32_t lo = (rb + 0x7FFFu + ((rb >> 16) & 1u)) >> 16;
  return (hi & 0xFFFFu) | (lo << 16);
}

__global__ __launch_bounds__(256) void split_kernel(const float* __restrict__ in,
                                                    uint32_t* __restrict__ out, int n4) {
  for (int i = blockIdx.x * blockDim.x + threadIdx.x; i < n4;
       i += gridDim.x * blockDim.x) {
    const float4 v = ((const float4*)in)[i];
    uint4 o;
    o.x = split_pack(v.x); o.y = split_pack(v.y);
    o.z = split_pack(v.z); o.w = split_pack(v.w);
    ((uint4*)out)[i] = o;
  }
}

// ---------------------------------------------------------------------------
// fp32 GEMM 64x64 tile (kept for the small M=4912 GEMMs).
// ---------------------------------------------------------------------------
__global__ __launch_bounds__(256) void gemm_nt_kernel(const float* __restrict__ A,
                                                      const float* __restrict__ W,
                                                      float* __restrict__ C, int M) {
  __shared__ float As[16][64];
  __shared__ float Ws[16][64];
  const int t   = threadIdx.x;
  const int m0  = blockIdx.x * 64;
  const int n0  = blockIdx.y * 64;
  const int lm  = t >> 2;
  const int lk4 = (t & 3) << 2;
  const int tx  = t & 15, ty = t >> 4;
  float acc[4][4] = {};
  const int am = m0 + lm;
  const float* Arow = A + (size_t)am * D_ + lk4;
  const float* Wrow = W + (size_t)(n0 + lm) * D_ + lk4;
  for (int d0 = 0; d0 < D_; d0 += 16) {
    float4 av = make_float4(0.f, 0.f, 0.f, 0.f);
    if (am < M) av = *(const float4*)(Arow + d0);
    const float4 wv = *(const float4*)(Wrow + d0);
    __syncthreads();
    As[lk4 + 0][lm] = av.x; As[lk4 + 1][lm] = av.y; As[lk4 + 2][lm] = av.z; As[lk4 + 3][lm] = av.w;
    Ws[lk4 + 0][lm] = wv.x; Ws[lk4 + 1][lm] = wv.y; Ws[lk4 + 2][lm] = wv.z; Ws[lk4 + 3][lm] = wv.w;
    __syncthreads();
#pragma unroll
    for (int kk = 0; kk < 16; kk++) {
      const float4 a = *(const float4*)&As[kk][ty * 4];
      const float4 w = *(const float4*)&Ws[kk][tx * 4];
      const float* ap = (const float*)&a;
      const float* wp = (const float*)&w;
#pragma unroll
      for (int i = 0; i < 4; i++)
#pragma unroll
        for (int j = 0; j < 4; j++) acc[i][j] += ap[i] * wp[j];
    }
  }
#pragma unroll
  for (int i = 0; i < 4; i++) {
    const int m = m0 + ty * 4 + i;
    if (m < M)
      *(float4*)(C + (size_t)m * D_ + n0 + tx * 4) =
          make_float4(acc[i][0], acc[i][1], acc[i][2], acc[i][3]);
  }
}

// ---------------------------------------------------------------------------
// Split-bf16 MFMA GEMM: C[m,n] = sum_k A[m,k]*W[n,k], fp32-accurate via
// 3 bf16 MFMAs (hi*hi + hi*lo + lo*hi). 128x128 tile, BK=32, 4 waves (2x2),
// each wave 64x64 via 4x4 frags of 16x16x32.
//  - A/B staged hi/lo-separated, [row][k] with row stride 40 bf16 (80 B):
//    frag ds_read_b128 is 2-way max (free).
//  - Staging: 256 threads x uint4 (4 k-words) x 4 row-iters = 128 rows x 32 k
//    for A and W each.  (Round-4 bug: only 2 row-iters -> half tile uninit.)
//  - k-consistency: both operands read k = 8*(lane>>4)+j. C/D map
//    (HW-verified): col=lane&15, row=(lane>>4)*4+reg.
// Requires M%128==0 (M=32768), N=D_=768 (grid.y=6), K=D_.
// ---------------------------------------------------------------------------
#define LDT 40
__global__ __launch_bounds__(256) void gemm_mfma_kernel(const uint32_t* __restrict__ Apk,
                                                        const uint32_t* __restrict__ Wpk,
                                                        float* __restrict__ C) {
  __shared__ short AsH[128 * LDT], AsL[128 * LDT];
  __shared__ short WsH[128 * LDT], WsL[128 * LDT];
  const int t    = threadIdx.x;
  const int m0   = blockIdx.x * 128, n0 = blockIdx.y * 128;
  const int lane = t & 63, wave = t >> 6;
  const int wm   = wave >> 1, wn = wave & 1;     // 2x2 wave grid
  const int lm   = lane & 15, lg = lane >> 4;    // frag row, k-group
  const int r0   = t >> 3, qi = t & 7;           // staging row (0..31) / k-quad

  uint4 abuf[4], wbuf[4];
  const uint32_t* Abase = Apk + (size_t)(m0 + r0) * D_ + qi * 4;
  const uint32_t* Wbase = Wpk + (size_t)(n0 + r0) * D_ + qi * 4;
  auto issue = [&](int d0) {
#pragma unroll
    for (int it = 0; it < 4; it++) {
      abuf[it] = *(const uint4*)(Abase + (size_t)(32 * it) * D_ + d0);
      wbuf[it] = *(const uint4*)(Wbase + (size_t)(32 * it) * D_ + d0);
    }
  };
  auto stage = [&]() {
#pragma unroll
    for (int it = 0; it < 4; it++) {
      const int r = r0 + 32 * it;
      const uint4 a = abuf[it], w = wbuf[it];
      uint2 ah = make_uint2((a.x & 0xFFFFu) | (a.y << 16), (a.z & 0xFFFFu) | (a.w << 16));
      uint2 al = make_uint2((a.x >> 16) | (a.y & 0xFFFF0000u), (a.z >> 16) | (a.w & 0xFFFF0000u));
      uint2 wh = make_uint2((w.x & 0xFFFFu) | (w.y << 16), (w.z & 0xFFFFu) | (w.w << 16));
      uint2 wl = make_uint2((w.x >> 16) | (w.y & 0xFFFF0000u), (w.z >> 16) | (w.w & 0xFFFF0000u));
      *(uint2*)(AsH + r * LDT + qi * 4) = ah;
      *(uint2*)(AsL + r * LDT + qi * 4) = al;
      *(uint2*)(WsH + r * LDT + qi * 4) = wh;
      *(uint2*)(WsL + r * LDT + qi * 4) = wl;
    }
  };

  floatx4 acc[4][4];
#pragma unroll
  for (int i = 0; i < 4; i++)
#pragma unroll
    for (int j = 0; j < 4; j++)
#pragma unroll
      for (int e = 0; e < 4; e++) acc[i][j][e] = 0.f;

  const short* aHb = AsH + (wm * 64 + lm) * LDT + lg * 8;
  const short* aLb = AsL + (wm * 64 + lm) * LDT + lg * 8;
  const short* wHb = WsH + (wn * 64 + lm) * LDT + lg * 8;
  const short* wLb = WsL + (wn * 64 + lm) * LDT + lg * 8;

  issue(0);
  for (int d0 = 0; d0 < D_; d0 += 32) {
    __syncthreads();
    stage();
    __syncthreads();
    if (d0 + 32 < D_) issue(d0 + 32);   // prefetch next slab under MFMAs
    short8v aH[4], aL[4], bH[4], bL[4];
#pragma unroll
    for (int i = 0; i < 4; i++) {
      aH[i] = *(const short8v*)(aHb + i * 16 * LDT);
      aL[i] = *(const short8v*)(aLb + i * 16 * LDT);
      bH[i] = *(const short8v*)(wHb + i * 16 * LDT);
      bL[i] = *(const short8v*)(wLb + i * 16 * LDT);
    }
#pragma unroll
    for (int i = 0; i < 4; i++)
#pragma unroll
      for (int j = 0; j < 4; j++) {
        acc[i][j] = __builtin_amdgcn_mfma_f32_16x16x32_bf16(aH[i], bH[j], acc[i][j], 0, 0, 0);
        acc[i][j] = __builtin_amdgcn_mfma_f32_16x16x32_bf16(aH[i], bL[j], acc[i][j], 0, 0, 0);
        acc[i][j] = __builtin_amdgcn_mfma_f32_16x16x32_bf16(aL[i], bH[j], acc[i][j], 0, 0, 0);
      }
  }
#pragma unroll
  for (int i = 0; i < 4; i++) {
    const int gm = m0 + wm * 64 + i * 16 + lg * 4;   // + e below (C/D map)
#pragma unroll
    for (int j = 0; j < 4; j++) {
      const int gn = n0 + wn * 64 + j * 16 + lm;
      float* cp = C + (size_t)gm * D_ + gn;
#pragma unroll
      for (int e = 0; e < 4; e++) cp[(size_t)e * D_] = acc[i][j][e];
    }
  }
}

// ---------------------------------------------------------------------------
// Fused flash attention (unchanged from round 3).
// ---------------------------------------------------------------------------
__global__ __launch_bounds__(256, 3) void attn_kernel(const float* __restrict__ q,
                                                      const float* __restrict__ kmat,
                                                      const float* __restrict__ vmat,
                                                      float* __restrict__ att,
                                                      float* __restrict__ ctx) {
  __shared__ float Qs[64][68];    // [dk][l]
  __shared__ float KVs[64][68];   // K phase: [dk][s] ; V phase: [s][dk]
  __shared__ float Ps[64][68];    // [l][s]
  const int t   = threadIdx.x;
  const int bid = blockIdx.x;
  const int lt  = bid / 192;            // 0..4
  const int bh  = bid - lt * 192;       // 0..191 -> same-XCD l-tiles per (b,h)
  const int h   = bh % H_;
  const int b   = bh / H_;
  const int l0  = lt * 64;
  const int tx  = t & 15, ty = t >> 4;
  const int lq  = t >> 2, cq = t & 3;

  {
    const int gl = l0 + lq;
#pragma unroll
    for (int p = 0; p < 4; p++) {
      const int dkc = (cq + 4 * p) * 4;
      float4 vq = make_float4(0.f, 0.f, 0.f, 0.f);
      if (gl < L_) vq = *(const float4*)(q + ((size_t)(b * L_ + gl)) * D_ + h * DK_ + dkc);
      Qs[dkc + 0][lq] = vq.x * INV_SCALE; Qs[dkc + 1][lq] = vq.y * INV_SCALE;
      Qs[dkc + 2][lq] = vq.z * INV_SCALE; Qs[dkc + 3][lq] = vq.w * INV_SCALE;
    }
  }

  const float* kbase = kmat + ((size_t)b * S_ + lq) * D_ + h * DK_;
  float4 kreg[4];
  auto issueK = [&](int s0) {
#pragma unroll
    for (int p = 0; p < 4; p++)
      kreg[p] = *(const float4*)(kbase + (size_t)s0 * D_ + (cq + 4 * p) * 4);
  };
  auto writeK = [&]() {
#pragma unroll
    for (int p = 0; p < 4; p++) {
      const int dkc = (cq + 4 * p) * 4;
      KVs[dkc + 0][lq] = kreg[p].x; KVs[dkc + 1][lq] = kreg[p].y;
      KVs[dkc + 2][lq] = kreg[p].z; KVs[dkc + 3][lq] = kreg[p].w;
    }
  };
  auto qk = [&](float (&acc)[4][4]) {
#pragma unroll 8
    for (int dk = 0; dk < 64; dk++) {
      const float4 a = *(const float4*)&Qs[dk][ty * 4];
      const float4 w = *(const float4*)&KVs[dk][tx * 4];
      const float* ap = (const float*)&a;
      const float* wp = (const float*)&w;
#pragma unroll
      for (int i = 0; i < 4; i++)
#pragma unroll
        for (int j = 0; j < 4; j++) acc[i][j] += ap[i] * wp[j];
    }
  };

  float m_run[4], s_run[4];
#pragma unroll
  for (int i = 0; i < 4; i++) { m_run[i] = -INFINITY; s_run[i] = 0.f; }

  // ================= Pass A: stats only =================
  issueK(0);
  for (int s0 = 0; s0 < S_; s0 += 64) {
    __syncthreads();
    writeK();
    __syncthreads();
    issueK((s0 + 64) & (S_ - 1));   // prefetch next (wraps to 0 for pass B)
    float acc[4][4] = {};
    qk(acc);
#pragma unroll
    for (int i = 0; i < 4; i++) {
      const float v0 = acc[i][0], v1 = acc[i][1], v2 = acc[i][2], v3 = acc[i][3];
      const float mt = fmaxf(fmaxf(v0, v1), fmaxf(v2, v3));
      if (mt > m_run[i]) { s_run[i] *= __expf(m_run[i] - mt); m_run[i] = mt; }
      s_run[i] += __expf(v0 - m_run[i]) + __expf(v1 - m_run[i]) +
                  __expf(v2 - m_run[i]) + __expf(v3 - m_run[i]);
    }
  }
#pragma unroll
  for (int i = 0; i < 4; i++) {
    float m = m_run[i];
#pragma unroll
    for (int o = 1; o < 16; o <<= 1) m = fmaxf(m, __shfl_xor(m, o));
    float s = s_run[i] * __expf(m_run[i] - m);
#pragma unroll
    for (int o = 1; o < 16; o <<= 1) s += __shfl_xor(s, o);
    m_run[i] = m;
    s_run[i] = 1.f / s;   // now holds inv_sum
  }

  // ================= Pass B: normalize + write att + P*V =================
  float ctxacc[4][4] = {};
  const size_t att_row0 = (size_t)(b * H_ + h) * L_;
  float4 vreg[4];
  auto issueV = [&](int s0) {
#pragma unroll
    for (int p = 0; p < 4; p++)
      vreg[p] = *(const float4*)(vmat + ((size_t)(b * S_ + s0 + ty + 16 * p)) * D_ +
                                 h * DK_ + tx * 4);
  };
  for (int s0 = 0; s0 < S_; s0 += 64) {
    __syncthreads();                       // prev PV done with KVs(V), Ps
    writeK();                              // kreg prefetched last iteration
    __syncthreads();
    issueV(s0);                            // V loads fly under QK compute
    float acc[4][4] = {};
    qk(acc);
#pragma unroll
    for (int i = 0; i < 4; i++) {
      float4 pv;
      pv.x = __expf(acc[i][0] - m_run[i]) * s_run[i];
      pv.y = __expf(acc[i][1] - m_run[i]) * s_run[i];
      pv.z = __expf(acc[i][2] - m_run[i]) * s_run[i];
      pv.w = __expf(acc[i][3] - m_run[i]) * s_run[i];
      *(float4*)&Ps[ty * 4 + i][tx * 4] = pv;
      const int gl = l0 + ty * 4 + i;
      if (gl < L_)
        __builtin_nontemporal_store(*(const nfloat4*)&pv,
            (nfloat4*)(att + (att_row0 + gl) * S_ + s0 + tx * 4));
    }
    __syncthreads();                       // Ps ready; KVs(K) no longer needed
#pragma unroll
    for (int p = 0; p < 4; p++)
      *(float4*)&KVs[ty + 16 * p][tx * 4] = vreg[p];
    __syncthreads();
    issueK((s0 + 64) & (S_ - 1));          // next K flies under PV compute
#pragma unroll 2
    for (int s4 = 0; s4 < 64; s4 += 4) {
      const float4 p0 = *(const float4*)&Ps[ty * 4 + 0][s4];
      const float4 p1 = *(const float4*)&Ps[ty * 4 + 1][s4];
      const float4 p2 = *(const float4*)&Ps[ty * 4 + 2][s4];
      const float4 p3 = *(const float4*)&Ps[ty * 4 + 3][s4];
      const float4 v0 = *(const float4*)&KVs[s4 + 0][tx * 4];
      const float4 v1 = *(const float4*)&KVs[s4 + 1][tx * 4];
      const float4 v2 = *(const float4*)&KVs[s4 + 2][tx * 4];
      const float4 v3 = *(const float4*)&KVs[s4 + 3][tx * 4];
#define PVROW(pi, r)                                                      \
      ctxacc[r][0] += pi.x * v0.x + pi.y * v1.x + pi.z * v2.x + pi.w * v3.x; \
      ctxacc[r][1] += pi.x * v0.y + pi.y * v1.y + pi.z * v2.y + pi.w * v3.y; \
      ctxacc[r][2] += pi.x * v0.z + pi.y * v1.z + pi.z * v2.z + pi.w * v3.z; \
      ctxacc[r][3] += pi.x * v0.w + pi.y * v1.w + pi.z * v2.w + pi.w * v3.w;
      PVROW(p0, 0) PVROW(p1, 1) PVROW(p2, 2) PVROW(p3, 3)
#undef PVROW
    }
  }
#pragma unroll
  for (int i = 0; i < 4; i++) {
    const int gl = l0 + ty * 4 + i;
    if (gl < L_)
      *(float4*)(ctx + ((size_t)(b * L_ + gl)) * D_ + h * DK_ + tx * 4) =
          make_float4(ctxacc[i][0], ctxacc[i][1], ctxacc[i][2], ctxacc[i][3]);
  }
}

// ---------------------------------------------------------------------------
extern "C" void kernel_launch(void* const* d_in, const int* in_sizes, int n_in,
                              void* d_out, int out_size, void* d_ws, size_t ws_size,
                              hipStream_t stream) {
  const float* x    = (const float*)d_in[0];
  const float* roll = (const float*)d_in[1];
  const float* Wq   = (const float*)d_in[2];
  const float* Wk   = (const float*)d_in[3];
  const float* Wv   = (const float*)d_in[4];
  const float* Wo   = (const float*)d_in[5];
  float* out = (float*)d_out;
  float* att = out + (size_t)B_ * L_ * D_;   // local_attention region of d_out

  char* ws = (char*)d_ws;
  size_t off = 0;
  auto take = [&](size_t bytes) -> void* {
    void* p = ws + off;
    off = (off + bytes + 255) & ~(size_t)255;
    return p;
  };
  int*      top_idx = (int*)     take((size_t)B_ * L_ * sizeof(int));
  float*    x_local = (float*)   take((size_t)B_ * L_ * D_ * sizeof(float));
  float*    qbuf    = (float*)   take((size_t)B_ * L_ * D_ * sizeof(float));
  float*    kbuf    = (float*)   take((size_t)B_ * S_ * D_ * sizeof(float));
  float*    vbuf    = (float*)   take((size_t)B_ * S_ * D_ * sizeof(float));
  float*    ctxbuf  = (float*)   take((size_t)B_ * L_ * D_ * sizeof(float));
  uint32_t* xsplit  = (uint32_t*)take((size_t)B_ * S_ * D_ * sizeof(uint32_t));
  uint32_t* wksplit = (uint32_t*)take((size_t)D_ * D_ * sizeof(uint32_t));
  uint32_t* wvsplit = (uint32_t*)take((size_t)D_ * D_ * sizeof(uint32_t));
  (void)in_sizes; (void)n_in; (void)out_size; (void)ws_size;

  topk_kernel  <<<B_, 256, 0, stream>>>(roll, top_idx);
  gather_kernel<<<B_ * L_, 192, 0, stream>>>(x, top_idx, x_local);
  split_kernel <<<2048, 256, 0, stream>>>(x,  xsplit,  B_ * S_ * D_ / 4);
  split_kernel <<<144,  256, 0, stream>>>(Wk, wksplit, D_ * D_ / 4);
  split_kernel <<<144,  256, 0, stream>>>(Wv, wvsplit, D_ * D_ / 4);
  gemm_mfma_kernel<<<dim3(256, 6), 256, 0, stream>>>(xsplit, wksplit, kbuf);
  gemm_mfma_kernel<<<dim3(256, 6), 256, 0, stream>>>(xsplit, wvsplit, vbuf);
  gemm_nt_kernel<<<dim3(77, 12), 256, 0, stream>>>(x_local, Wq, qbuf, B_ * L_);
  attn_kernel  <<<dim3(5 * 192), 256, 0, stream>>>(qbuf, kbuf, vbuf, att, ctxbuf);
  gemm_nt_kernel<<<dim3(77, 12), 256, 0, stream>>>(ctxbuf, Wo, out, B_ * L_);
}